// Round 3
// baseline (170.992 us; speedup 1.0000x reference)
//
#include <hip/hip_runtime.h>

// Sliding-window attention: x@Wqkv -> SWA(win=64, zero-pad in softmax) -> @Wout
// B=2 S=2048 DIM=512 H=8 HD=64. All GEMMs in f16 MFMA (threshold is bf16-scale).

#define S_SZ   2048
#define DIMM   512
#define NH     8
#define HDIM   64
#define MROWS  4096      // B*S
#define NQKV   1536      // 3*DIM

typedef _Float16 half8 __attribute__((ext_vector_type(8)));
typedef _Float16 half4 __attribute__((ext_vector_type(4)));
typedef float    f32x4 __attribute__((ext_vector_type(4)));

// ---------- prep: f32 -> f16 elementwise ----------
__global__ void convert_f32_f16(const float* __restrict__ in, _Float16* __restrict__ out, int n) {
  int i = (blockIdx.x * blockDim.x + threadIdx.x) * 4;
  if (i + 3 < n) {
    float4 v = *reinterpret_cast<const float4*>(in + i);
    half4 h;
    h[0] = (_Float16)v.x; h[1] = (_Float16)v.y; h[2] = (_Float16)v.z; h[3] = (_Float16)v.w;
    *reinterpret_cast<half4*>(out + i) = h;
  }
}

// ---------- prep: transpose f32 [K][N] -> f16 [N][K] ----------
__global__ void transpose_to_f16(const float* __restrict__ in, _Float16* __restrict__ out,
                                 int K, int N) {
  __shared__ float tile[32][33];
  int n0 = blockIdx.x * 32, k0 = blockIdx.y * 32;
  int tx = threadIdx.x & 31, ty = threadIdx.x >> 5;   // 32 x 8
#pragma unroll
  for (int i = 0; i < 4; i++) {
    int k = ty + i * 8;
    tile[k][tx] = in[(size_t)(k0 + k) * N + n0 + tx];
  }
  __syncthreads();
#pragma unroll
  for (int i = 0; i < 4; i++) {
    int n = ty + i * 8;
    out[(size_t)(n0 + n) * K + k0 + tx] = (_Float16)tile[tx][n];
  }
}

// ---------- GEMM: C[M][N] = A[M][K] * BT[N][K]^T, f16 inputs, MFMA 16x16x32 ----------
// 128x128 tile, BK=32, 256 threads = 4 waves (2x2), each wave 64x64 (4x4 fragments).
template <bool C_F16>
__global__ __launch_bounds__(256) void gemm_f16(const _Float16* __restrict__ A,
                                                const _Float16* __restrict__ BT,
                                                void* __restrict__ C,
                                                int M, int N, int K) {
  const int LDA = 40;  // 32 + 8 pad: row stride 80B -> conflict-free b128 frag reads
  __shared__ _Float16 As[128 * 40];
  __shared__ _Float16 Bs[128 * 40];

  const int brow = blockIdx.y * 128, bcol = blockIdx.x * 128;
  const int tid = threadIdx.x;
  const int lane = tid & 63, wid = tid >> 6;
  const int wm = (wid >> 1) * 64, wn = (wid & 1) * 64;

  f32x4 acc[4][4] = {};

  const int r  = tid >> 2;   // 0..63
  const int cg = tid & 3;    // 8-elem column group

  for (int kt = 0; kt < K; kt += 32) {
    // stage 128x32 of A and BT (reg-staged, converted layout is k-contiguous)
    half8 a0 = *(const half8*)(A  + (size_t)(brow + r)      * K + kt + cg * 8);
    half8 a1 = *(const half8*)(A  + (size_t)(brow + r + 64) * K + kt + cg * 8);
    half8 b0 = *(const half8*)(BT + (size_t)(bcol + r)      * K + kt + cg * 8);
    half8 b1 = *(const half8*)(BT + (size_t)(bcol + r + 64) * K + kt + cg * 8);
    __syncthreads();  // previous iter's fragment reads complete
    *(half8*)(As + r        * LDA + cg * 8) = a0;
    *(half8*)(As + (r + 64) * LDA + cg * 8) = a1;
    *(half8*)(Bs + r        * LDA + cg * 8) = b0;
    *(half8*)(Bs + (r + 64) * LDA + cg * 8) = b1;
    __syncthreads();

    const int fr = lane & 15, kb = (lane >> 4) * 8;
    half8 af[4], bf[4];
#pragma unroll
    for (int m = 0; m < 4; m++) af[m] = *(const half8*)(As + (wm + m * 16 + fr) * LDA + kb);
#pragma unroll
    for (int n = 0; n < 4; n++) bf[n] = *(const half8*)(Bs + (wn + n * 16 + fr) * LDA + kb);
#pragma unroll
    for (int m = 0; m < 4; m++)
#pragma unroll
      for (int n = 0; n < 4; n++)
        acc[m][n] = __builtin_amdgcn_mfma_f32_16x16x32_f16(af[m], bf[n], acc[m][n], 0, 0, 0);
  }

  // C/D layout: col = lane&15, row = (lane>>4)*4 + j   [verified m89/m91]
  const int fq = lane >> 4, fr = lane & 15;
#pragma unroll
  for (int m = 0; m < 4; m++)
#pragma unroll
    for (int n = 0; n < 4; n++)
#pragma unroll
      for (int j = 0; j < 4; j++) {
        int rr = brow + wm + m * 16 + fq * 4 + j;
        int cc = bcol + wn + n * 16 + fr;
        if (C_F16) ((_Float16*)C)[(size_t)rr * N + cc] = (_Float16)acc[m][n][j];
        else       ((float*)C)[(size_t)rr * N + cc]    = acc[m][n][j];
      }
}

// ---------- sliding-window attention ----------
// Block = (64 queries) x (1 head) x (1 batch); 4 waves, each wave does 16 queries.
// Per query: lane = window slot for scores+softmax, lane = head-dim for PV.
// Zero rows staged for out-of-range keys -> score 0 kept in softmax (matches ref pad).
__global__ __launch_bounds__(256) void attn_kernel(const _Float16* __restrict__ qkv,
                                                   _Float16* __restrict__ attn_out) {
  __shared__ float Ks[127 * 65];  // rows qs0-32 .. qs0+94, stride 65 (2-way bank = free)
  __shared__ float Vs[127 * 65];

  const int b = blockIdx.z, h = blockIdx.y, qs0 = blockIdx.x * 64;
  const int kv0 = qs0 - 32;
  const int tid = threadIdx.x;

  // stage K,V windows (f16 global -> f32 LDS), 127 rows x 64 dims, 4 dims/group
  for (int idx = tid; idx < 127 * 16; idx += 256) {
    const int rr = idx >> 4, cg = idx & 15;
    const int s = kv0 + rr;
    float k0 = 0.f, k1 = 0.f, k2 = 0.f, k3 = 0.f;
    float v0 = 0.f, v1 = 0.f, v2 = 0.f, v3 = 0.f;
    if (s >= 0 && s < S_SZ) {
      const size_t base = (size_t)(b * S_SZ + s) * NQKV + h * HDIM + cg * 4;
      half4 kk = *(const half4*)(qkv + base + DIMM);
      half4 vv = *(const half4*)(qkv + base + 2 * DIMM);
      k0 = (float)kk[0]; k1 = (float)kk[1]; k2 = (float)kk[2]; k3 = (float)kk[3];
      v0 = (float)vv[0]; v1 = (float)vv[1]; v2 = (float)vv[2]; v3 = (float)vv[3];
    }
    float* kd = Ks + rr * 65 + cg * 4;
    float* vd = Vs + rr * 65 + cg * 4;
    kd[0] = k0; kd[1] = k1; kd[2] = k2; kd[3] = k3;
    vd[0] = v0; vd[1] = v1; vd[2] = v2; vd[3] = v3;
  }
  __syncthreads();

  const int lane = tid & 63, wid = tid >> 6;
#pragma unroll 1
  for (int qq = 0; qq < 16; ++qq) {
    const int qi = wid * 16 + qq;
    const int sq = qs0 + qi;
    const float qd = (float)qkv[(size_t)(b * S_SZ + sq) * NQKV + h * HDIM + lane];

    // scores: lane w covers key row (qi + w) in LDS
    float sc = 0.f;
    const int kbase = (qi + lane) * 65;
#pragma unroll
    for (int d = 0; d < 64; d++) sc += __shfl(qd, d) * Ks[kbase + d];
    sc *= 0.125f;  // 1/sqrt(64)

    // softmax over the 64 lanes
    float mx = sc;
#pragma unroll
    for (int off = 32; off; off >>= 1) mx = fmaxf(mx, __shfl_xor(mx, off));
    float p = __expf(sc - mx);
    float sum = p;
#pragma unroll
    for (int off = 32; off; off >>= 1) sum += __shfl_xor(sum, off);
    p /= sum;

    // PV: lane d accumulates sum_w attn_w * V[w][d]
    float o = 0.f;
#pragma unroll
    for (int w = 0; w < 64; w++) o += __shfl(p, w) * Vs[(qi + w) * 65 + lane];

    attn_out[(size_t)(b * S_SZ + sq) * DIMM + h * HDIM + lane] = (_Float16)o;
  }
}

// ---------- launch ----------
extern "C" void kernel_launch(void* const* d_in, const int* in_sizes, int n_in,
                              void* d_out, int out_size, void* d_ws, size_t ws_size,
                              hipStream_t stream) {
  const float* x    = (const float*)d_in[0];
  const float* Wqkv = (const float*)d_in[1];
  const float* Wout = (const float*)d_in[2];

  char* ws = (char*)d_ws;
  _Float16* xb    = (_Float16*)(ws);                 // 4096*512  f16 =  4 MB
  _Float16* WqkvT = (_Float16*)(ws + 4194304);       // 1536*512  f16 = 1.5 MB
  _Float16* WoutT = (_Float16*)(ws + 5767168);       //  512*512  f16 = 0.5 MB
  _Float16* qkv   = (_Float16*)(ws + 6291456);       // 4096*1536 f16 = 12 MB
  _Float16* attn  = (_Float16*)(ws + 18874368);      // 4096*512  f16 =  4 MB

  convert_f32_f16<<<2048, 256, 0, stream>>>(x, xb, MROWS * DIMM);
  transpose_to_f16<<<dim3(48, 16), 256, 0, stream>>>(Wqkv, WqkvT, DIMM, NQKV);
  transpose_to_f16<<<dim3(16, 16), 256, 0, stream>>>(Wout, WoutT, DIMM, DIMM);

  gemm_f16<true><<<dim3(12, 32), 256, 0, stream>>>(xb, WqkvT, (void*)qkv, MROWS, NQKV, DIMM);
  attn_kernel<<<dim3(32, NH, 2), 256, 0, stream>>>(qkv, attn);
  gemm_f16<false><<<dim3(4, 32), 256, 0, stream>>>(attn, WoutT, d_out, MROWS, DIMM, DIMM);
}

// Round 8
// 111.726 us; speedup vs baseline: 1.5305x; 1.5305x over previous
//
#include <hip/hip_runtime.h>

// Sliding-window attention: x@Wqkv -> SWA(win=64, zero-pad in softmax) -> @Wout
// B=2 S=2048 DIM=512 H=8 HD=64. All GEMMs + attention in f16 MFMA.

#define S_SZ   2048
#define DIMM   512
#define NH     8
#define HDIM   64
#define MROWS  4096      // B*S
#define NQKV   1536      // 3*DIM

typedef _Float16 half8 __attribute__((ext_vector_type(8)));
typedef _Float16 half4 __attribute__((ext_vector_type(4)));
typedef float    f32x4 __attribute__((ext_vector_type(4)));

// ---------- prep: f32 -> f16 elementwise ----------
__global__ void convert_f32_f16(const float* __restrict__ in, _Float16* __restrict__ out, int n) {
  int i = (blockIdx.x * blockDim.x + threadIdx.x) * 4;
  if (i + 3 < n) {
    float4 v = *reinterpret_cast<const float4*>(in + i);
    half4 h;
    h[0] = (_Float16)v.x; h[1] = (_Float16)v.y; h[2] = (_Float16)v.z; h[3] = (_Float16)v.w;
    *reinterpret_cast<half4*>(out + i) = h;
  }
}

// ---------- prep: transpose f32 [K][N] -> f16 [N][K] ----------
__global__ void transpose_to_f16(const float* __restrict__ in, _Float16* __restrict__ out,
                                 int K, int N) {
  __shared__ float tile[32][33];
  int n0 = blockIdx.x * 32, k0 = blockIdx.y * 32;
  int tx = threadIdx.x & 31, ty = threadIdx.x >> 5;   // 32 x 8
#pragma unroll
  for (int i = 0; i < 4; i++) {
    int k = ty + i * 8;
    tile[k][tx] = in[(size_t)(k0 + k) * N + n0 + tx];
  }
  __syncthreads();
#pragma unroll
  for (int i = 0; i < 4; i++) {
    int n = ty + i * 8;
    out[(size_t)(n0 + n) * K + k0 + tx] = (_Float16)tile[tx][n];
  }
}

// ---------- GEMM: C[M][N] = A[M][K] * BT[N][K]^T, f16 inputs, MFMA 16x16x32 ----------
template <bool C_F16>
__global__ __launch_bounds__(256) void gemm_f16(const _Float16* __restrict__ A,
                                                const _Float16* __restrict__ BT,
                                                void* __restrict__ C,
                                                int M, int N, int K) {
  const int LDA = 40;  // 32 + 8 pad
  __shared__ _Float16 As[128 * 40];
  __shared__ _Float16 Bs[128 * 40];

  const int brow = blockIdx.y * 128, bcol = blockIdx.x * 128;
  const int tid = threadIdx.x;
  const int lane = tid & 63, wid = tid >> 6;
  const int wm = (wid >> 1) * 64, wn = (wid & 1) * 64;

  f32x4 acc[4][4] = {};

  const int r  = tid >> 2;   // 0..63
  const int cg = tid & 3;    // 8-elem column group

  for (int kt = 0; kt < K; kt += 32) {
    half8 a0 = *(const half8*)(A  + (size_t)(brow + r)      * K + kt + cg * 8);
    half8 a1 = *(const half8*)(A  + (size_t)(brow + r + 64) * K + kt + cg * 8);
    half8 b0 = *(const half8*)(BT + (size_t)(bcol + r)      * K + kt + cg * 8);
    half8 b1 = *(const half8*)(BT + (size_t)(bcol + r + 64) * K + kt + cg * 8);
    __syncthreads();
    *(half8*)(As + r        * LDA + cg * 8) = a0;
    *(half8*)(As + (r + 64) * LDA + cg * 8) = a1;
    *(half8*)(Bs + r        * LDA + cg * 8) = b0;
    *(half8*)(Bs + (r + 64) * LDA + cg * 8) = b1;
    __syncthreads();

    const int fr = lane & 15, kb = (lane >> 4) * 8;
    half8 af[4], bf[4];
#pragma unroll
    for (int m = 0; m < 4; m++) af[m] = *(const half8*)(As + (wm + m * 16 + fr) * LDA + kb);
#pragma unroll
    for (int n = 0; n < 4; n++) bf[n] = *(const half8*)(Bs + (wn + n * 16 + fr) * LDA + kb);
#pragma unroll
    for (int m = 0; m < 4; m++)
#pragma unroll
      for (int n = 0; n < 4; n++)
        acc[m][n] = __builtin_amdgcn_mfma_f32_16x16x32_f16(af[m], bf[n], acc[m][n], 0, 0, 0);
  }

  const int fq = lane >> 4, fr = lane & 15;
#pragma unroll
  for (int m = 0; m < 4; m++)
#pragma unroll
    for (int n = 0; n < 4; n++)
#pragma unroll
      for (int j = 0; j < 4; j++) {
        int rr = brow + wm + m * 16 + fq * 4 + j;
        int cc = bcol + wn + n * 16 + fr;
        if (C_F16) ((_Float16*)C)[(size_t)rr * N + cc] = (_Float16)acc[m][n][j];
        else       ((float*)C)[(size_t)rr * N + cc]    = acc[m][n][j];
      }
}

// ---------- MFMA sliding-window attention ----------
// Block = (64 queries) x head x batch, 4 waves; wave w owns queries 16w..16w+15.
// S^T = K·Q^T per wave (8 key-tiles x 2 k-slices = 16 MFMAs); softmax in-register
// (lane holds 32 key-scores for ONE query; band-masked; reduce over 4 g-lanes via
// shfl_xor 16/32); P (f16) + V^T staged in XOR-swizzled LDS; O = P·V (16 MFMAs).
// OOB keys -> zero rows -> score 0 kept in softmax (matches reference zero-pad).

// XOR swizzle: spreads banks for both write phases (vary d>>3) and fragment-read
// phases (vary d&7). Row stride 128 halves; returns half-index. 8B align preserved.
__device__ __forceinline__ int swz(int row, int colh) {
  int key = ((row & 7) ^ ((row >> 3) & 7)) << 4;
  return row * 128 + (((colh * 2) ^ key) >> 1);
}

__global__ __launch_bounds__(256) void attn_mfma(const _Float16* __restrict__ qkv,
                                                 _Float16* __restrict__ attn_out) {
  __shared__ _Float16 Vt[64 * 128];   // V^T: [dim][key], swizzled
  __shared__ _Float16 Pl[64 * 128];   // P:   [query][key], swizzled

  const int b = blockIdx.z, h = blockIdx.y, q0 = blockIdx.x * 64;
  const int kv0 = q0 - 32;
  const int tid = threadIdx.x;
  const int lane = tid & 63, w = tid >> 6;
  const int fr = lane & 15, g = lane >> 4;

  // ---- stage V^T: thread t -> keys 4*(t>>3)..+3, dims 8*(t&7)..+7 (coalesced reads)
  {
    const int jg = tid >> 3, dg = tid & 7;
    half8 vv[4];
#pragma unroll
    for (int i = 0; i < 4; i++) {
      int s = kv0 + jg * 4 + i;
      half8 z = {};
      if (s >= 0 && s < S_SZ)
        z = *(const half8*)(qkv + (size_t)(b * S_SZ + s) * NQKV + 2 * DIMM + h * HDIM + dg * 8);
      vv[i] = z;
    }
#pragma unroll
    for (int i2 = 0; i2 < 8; i2++) {
      half4 o;
      o[0] = vv[0][i2]; o[1] = vv[1][i2]; o[2] = vv[2][i2]; o[3] = vv[3][i2];
      *(half4*)(Vt + swz(dg * 8 + i2, jg * 4)) = o;
    }
  }

  // ---- S^T = K·Q^T, fragments direct from global (L2-resident)
  const _Float16* qbase = qkv + (size_t)(b * S_SZ + q0 + 16 * w + fr) * NQKV + h * HDIM;
  half8 bq0 = *(const half8*)(qbase + 8 * g);        // dims  8g..+7
  half8 bq1 = *(const half8*)(qbase + 32 + 8 * g);   // dims 32+8g..+7

  f32x4 st[8];
#pragma unroll
  for (int kt = 0; kt < 8; kt++) st[kt] = (f32x4){0.f, 0.f, 0.f, 0.f};

#pragma unroll
  for (int kt = 0; kt < 8; kt++) {
    int s = kv0 + 16 * kt + fr;
    half8 a0 = {}, a1 = {};
    if (s >= 0 && s < S_SZ) {
      const _Float16* kb = qkv + (size_t)(b * S_SZ + s) * NQKV + DIMM + h * HDIM;
      a0 = *(const half8*)(kb + 8 * g);
      a1 = *(const half8*)(kb + 32 + 8 * g);
    }
    st[kt] = __builtin_amdgcn_mfma_f32_16x16x32_f16(a0, bq0, st[kt], 0, 0, 0);
    st[kt] = __builtin_amdgcn_mfma_f32_16x16x32_f16(a1, bq1, st[kt], 0, 0, 0);
  }

  // ---- softmax over band [qi, qi+63]; lane's keys: 16kt+4g+j, query col = qi
  const int qi = 16 * w + fr;
  float m = -1e30f;
#pragma unroll
  for (int kt = 0; kt < 8; kt++)
#pragma unroll
    for (int j = 0; j < 4; j++) {
      int krel = 16 * kt + 4 * g + j;
      float scv = st[kt][j] * 0.125f;   // 1/sqrt(64)
      st[kt][j] = scv;
      if (krel >= qi && krel < qi + 64) m = fmaxf(m, scv);
    }
  m = fmaxf(m, __shfl_xor(m, 16));
  m = fmaxf(m, __shfl_xor(m, 32));
  float sum = 0.f;
#pragma unroll
  for (int kt = 0; kt < 8; kt++)
#pragma unroll
    for (int j = 0; j < 4; j++) {
      int krel = 16 * kt + 4 * g + j;
      float p = (krel >= qi && krel < qi + 64) ? __expf(st[kt][j] - m) : 0.f;
      st[kt][j] = p;
      sum += p;
    }
  sum += __shfl_xor(sum, 16);
  sum += __shfl_xor(sum, 32);
  const float inv = 1.f / sum;
#pragma unroll
  for (int kt = 0; kt < 8; kt++) {
    half4 o;
#pragma unroll
    for (int j = 0; j < 4; j++) o[j] = (_Float16)(st[kt][j] * inv);
    *(half4*)(Pl + swz(qi, 16 * kt + 4 * g)) = o;
  }

  __syncthreads();   // covers Vt staging + Pl writes

  // ---- O = P·V
  f32x4 acc[4];
#pragma unroll
  for (int dt = 0; dt < 4; dt++) acc[dt] = (f32x4){0.f, 0.f, 0.f, 0.f};
  half8 ap[4];
#pragma unroll
  for (int ks = 0; ks < 4; ks++)
    ap[ks] = *(const half8*)(Pl + swz(16 * w + fr, 32 * ks + 8 * g));
#pragma unroll
  for (int dt = 0; dt < 4; dt++)
#pragma unroll
    for (int ks = 0; ks < 4; ks++) {
      half8 bv = *(const half8*)(Vt + swz(16 * dt + fr, 32 * ks + 8 * g));
      acc[dt] = __builtin_amdgcn_mfma_f32_16x16x32_f16(ap[ks], bv, acc[dt], 0, 0, 0);
    }

  // ---- store O: col = 16dt+fr, row = 16w + 4g + j
#pragma unroll
  for (int dt = 0; dt < 4; dt++)
#pragma unroll
    for (int j = 0; j < 4; j++) {
      int q = q0 + 16 * w + 4 * g + j;
      attn_out[(size_t)(b * S_SZ + q) * DIMM + h * HDIM + 16 * dt + fr] = (_Float16)acc[dt][j];
    }
}

// ---------- launch ----------
extern "C" void kernel_launch(void* const* d_in, const int* in_sizes, int n_in,
                              void* d_out, int out_size, void* d_ws, size_t ws_size,
                              hipStream_t stream) {
  const float* x    = (const float*)d_in[0];
  const float* Wqkv = (const float*)d_in[1];
  const float* Wout = (const float*)d_in[2];

  char* ws = (char*)d_ws;
  _Float16* xb    = (_Float16*)(ws);                 // 4096*512  f16 =  4 MB
  _Float16* WqkvT = (_Float16*)(ws + 4194304);       // 1536*512  f16 = 1.5 MB
  _Float16* WoutT = (_Float16*)(ws + 5767168);       //  512*512  f16 = 0.5 MB
  _Float16* qkv   = (_Float16*)(ws + 6291456);       // 4096*1536 f16 = 12 MB
  _Float16* attn  = (_Float16*)(ws + 18874368);      // 4096*512  f16 =  4 MB

  convert_f32_f16<<<2048, 256, 0, stream>>>(x, xb, MROWS * DIMM);
  transpose_to_f16<<<dim3(48, 16), 256, 0, stream>>>(Wqkv, WqkvT, DIMM, NQKV);
  transpose_to_f16<<<dim3(16, 16), 256, 0, stream>>>(Wout, WoutT, DIMM, DIMM);

  gemm_f16<true><<<dim3(12, 32), 256, 0, stream>>>(xb, WqkvT, (void*)qkv, MROWS, NQKV, DIMM);
  attn_mfma<<<dim3(32, NH, 2), 256, 0, stream>>>(qkv, attn);
  gemm_f16<false><<<dim3(4, 32), 256, 0, stream>>>(attn, WoutT, d_out, MROWS, DIMM, DIMM);
}

// Round 10
// 111.005 us; speedup vs baseline: 1.5404x; 1.0065x over previous
//
#include <hip/hip_runtime.h>

// Sliding-window attention: x@Wqkv -> SWA(win=64, zero-pad in softmax) -> @Wout
// B=2 S=2048 DIM=512 H=8 HD=64. All GEMMs + attention in f16 MFMA.
// R8: GEMM staging via global_load_lds width-16 (m97 structure, linear LDS).

#define S_SZ   2048
#define DIMM   512
#define NH     8
#define HDIM   64
#define MROWS  4096      // B*S
#define NQKV   1536      // 3*DIM

typedef _Float16 half8 __attribute__((ext_vector_type(8)));
typedef _Float16 half4 __attribute__((ext_vector_type(4)));
typedef float    f32x4 __attribute__((ext_vector_type(4)));

// async global->LDS, 16B per lane; LDS dest is wave-uniform base + lane*16
#define GLOAD16(g, l)                                                          \
  __builtin_amdgcn_global_load_lds(                                            \
      (const __attribute__((address_space(1))) void*)(g),                      \
      (__attribute__((address_space(3))) void*)(l), 16, 0, 0)

// ---------- prep: f32 -> f16 elementwise ----------
__global__ void convert_f32_f16(const float* __restrict__ in, _Float16* __restrict__ out, int n) {
  int i = (blockIdx.x * blockDim.x + threadIdx.x) * 4;
  if (i + 3 < n) {
    float4 v = *reinterpret_cast<const float4*>(in + i);
    half4 h;
    h[0] = (_Float16)v.x; h[1] = (_Float16)v.y; h[2] = (_Float16)v.z; h[3] = (_Float16)v.w;
    *reinterpret_cast<half4*>(out + i) = h;
  }
}

// ---------- prep: transpose f32 [K][N] -> f16 [N][K] ----------
__global__ void transpose_to_f16(const float* __restrict__ in, _Float16* __restrict__ out,
                                 int K, int N) {
  __shared__ float tile[32][33];
  int n0 = blockIdx.x * 32, k0 = blockIdx.y * 32;
  int tx = threadIdx.x & 31, ty = threadIdx.x >> 5;   // 32 x 8
#pragma unroll
  for (int i = 0; i < 4; i++) {
    int k = ty + i * 8;
    tile[k][tx] = in[(size_t)(k0 + k) * N + n0 + tx];
  }
  __syncthreads();
#pragma unroll
  for (int i = 0; i < 4; i++) {
    int n = ty + i * 8;
    out[(size_t)(n0 + n) * K + k0 + tx] = (_Float16)tile[tx][n];
  }
}

// ---------- GEMM: C[M][N] = A[M][K] * BT[N][K]^T, f16, MFMA 16x16x32 ----------
// 128x128 tile, BK=32, 4 waves (2x2), 64x64/wave. Staging: global_load_lds w16,
// linear LDS LDA=32 (m97 structure). Wave w stages rows 32w..32w+31 of A and BT
// as 2 chunks x 1KB (16 rows each); lane l -> row (l>>2), col-halfs (l&3)*8.
template <bool C_F16>
__global__ __launch_bounds__(256) void gemm_f16(const _Float16* __restrict__ A,
                                                const _Float16* __restrict__ BT,
                                                void* __restrict__ C,
                                                int M, int N, int K) {
  __shared__ _Float16 As[128 * 32];
  __shared__ _Float16 Bs[128 * 32];

  const int brow = blockIdx.y * 128, bcol = blockIdx.x * 128;
  const int tid = threadIdx.x;
  const int lane = tid & 63, wid = tid >> 6;
  const int wm = (wid >> 1) * 64, wn = (wid & 1) * 64;

  f32x4 acc[4][4] = {};

  const int srow = wid * 32 + (lane >> 2);   // staged row (chunk 0); chunk 1 = +16
  const int scol = (lane & 3) * 8;           // staged col (halfs)
  _Float16* lA = As + wid * 1024;            // wave-uniform chunk bases (halfs)
  _Float16* lB = Bs + wid * 1024;

  const int fr = lane & 15, kb = (lane >> 4) * 8;

  for (int kt = 0; kt < K; kt += 32) {
    const _Float16* ga = A  + (size_t)(brow + srow) * K + kt + scol;
    const _Float16* gb = BT + (size_t)(bcol + srow) * K + kt + scol;
    GLOAD16(ga, lA);
    GLOAD16(ga + (size_t)16 * K, lA + 512);
    GLOAD16(gb, lB);
    GLOAD16(gb + (size_t)16 * K, lB + 512);
    __syncthreads();   // drains vmcnt (gload) for all waves

    half8 af[4], bf[4];
#pragma unroll
    for (int m = 0; m < 4; m++) af[m] = *(const half8*)(As + (wm + m * 16 + fr) * 32 + kb);
#pragma unroll
    for (int n = 0; n < 4; n++) bf[n] = *(const half8*)(Bs + (wn + n * 16 + fr) * 32 + kb);
#pragma unroll
    for (int m = 0; m < 4; m++)
#pragma unroll
      for (int n = 0; n < 4; n++)
        acc[m][n] = __builtin_amdgcn_mfma_f32_16x16x32_f16(af[m], bf[n], acc[m][n], 0, 0, 0);
    __syncthreads();   // frag reads done before next iter's staging overwrites
  }

  // C/D layout: col = lane&15, row = (lane>>4)*4 + j   [verified m89/m91]
  const int fq = lane >> 4;
#pragma unroll
  for (int m = 0; m < 4; m++)
#pragma unroll
    for (int n = 0; n < 4; n++)
#pragma unroll
      for (int j = 0; j < 4; j++) {
        int rr = brow + wm + m * 16 + fq * 4 + j;
        int cc = bcol + wn + n * 16 + fr;
        if (C_F16) ((_Float16*)C)[(size_t)rr * N + cc] = (_Float16)acc[m][n][j];
        else       ((float*)C)[(size_t)rr * N + cc]    = acc[m][n][j];
      }
}

// ---------- MFMA sliding-window attention ----------
// Block = (64 queries) x head x batch, 4 waves; wave w owns queries 16w..16w+15.
// S^T = K·Q^T per wave; softmax in-register (band-masked, shfl_xor 16/32 reduce);
// P (f16) + V^T staged in XOR-swizzled LDS; O = P·V.
// OOB keys -> zero rows -> score 0 kept in softmax (matches reference zero-pad).
__device__ __forceinline__ int swz(int row, int colh) {
  int key = ((row & 7) ^ ((row >> 3) & 7)) << 4;
  return row * 128 + (((colh * 2) ^ key) >> 1);
}

__global__ __launch_bounds__(256) void attn_mfma(const _Float16* __restrict__ qkv,
                                                 _Float16* __restrict__ attn_out) {
  __shared__ _Float16 Vt[64 * 128];   // V^T: [dim][key], swizzled
  __shared__ _Float16 Pl[64 * 128];   // P:   [query][key], swizzled

  const int b = blockIdx.z, h = blockIdx.y, q0 = blockIdx.x * 64;
  const int kv0 = q0 - 32;
  const int tid = threadIdx.x;
  const int lane = tid & 63, w = tid >> 6;
  const int fr = lane & 15, g = lane >> 4;

  // ---- stage V^T
  {
    const int jg = tid >> 3, dg = tid & 7;
    half8 vv[4];
#pragma unroll
    for (int i = 0; i < 4; i++) {
      int s = kv0 + jg * 4 + i;
      half8 z = {};
      if (s >= 0 && s < S_SZ)
        z = *(const half8*)(qkv + (size_t)(b * S_SZ + s) * NQKV + 2 * DIMM + h * HDIM + dg * 8);
      vv[i] = z;
    }
#pragma unroll
    for (int i2 = 0; i2 < 8; i2++) {
      half4 o;
      o[0] = vv[0][i2]; o[1] = vv[1][i2]; o[2] = vv[2][i2]; o[3] = vv[3][i2];
      *(half4*)(Vt + swz(dg * 8 + i2, jg * 4)) = o;
    }
  }

  // ---- S^T = K·Q^T
  const _Float16* qbase = qkv + (size_t)(b * S_SZ + q0 + 16 * w + fr) * NQKV + h * HDIM;
  half8 bq0 = *(const half8*)(qbase + 8 * g);
  half8 bq1 = *(const half8*)(qbase + 32 + 8 * g);

  f32x4 st[8];
#pragma unroll
  for (int kt = 0; kt < 8; kt++) st[kt] = (f32x4){0.f, 0.f, 0.f, 0.f};

#pragma unroll
  for (int kt = 0; kt < 8; kt++) {
    int s = kv0 + 16 * kt + fr;
    half8 a0 = {}, a1 = {};
    if (s >= 0 && s < S_SZ) {
      const _Float16* kb2 = qkv + (size_t)(b * S_SZ + s) * NQKV + DIMM + h * HDIM;
      a0 = *(const half8*)(kb2 + 8 * g);
      a1 = *(const half8*)(kb2 + 32 + 8 * g);
    }
    st[kt] = __builtin_amdgcn_mfma_f32_16x16x32_f16(a0, bq0, st[kt], 0, 0, 0);
    st[kt] = __builtin_amdgcn_mfma_f32_16x16x32_f16(a1, bq1, st[kt], 0, 0, 0);
  }

  // ---- softmax over band [qi, qi+63]
  const int qi = 16 * w + fr;
  float m = -1e30f;
#pragma unroll
  for (int kt = 0; kt < 8; kt++)
#pragma unroll
    for (int j = 0; j < 4; j++) {
      int krel = 16 * kt + 4 * g + j;
      float scv = st[kt][j] * 0.125f;
      st[kt][j] = scv;
      if (krel >= qi && krel < qi + 64) m = fmaxf(m, scv);
    }
  m = fmaxf(m, __shfl_xor(m, 16));
  m = fmaxf(m, __shfl_xor(m, 32));
  float sum = 0.f;
#pragma unroll
  for (int kt = 0; kt < 8; kt++)
#pragma unroll
    for (int j = 0; j < 4; j++) {
      int krel = 16 * kt + 4 * g + j;
      float p = (krel >= qi && krel < qi + 64) ? __expf(st[kt][j] - m) : 0.f;
      st[kt][j] = p;
      sum += p;
    }
  sum += __shfl_xor(sum, 16);
  sum += __shfl_xor(sum, 32);
  const float inv = 1.f / sum;
#pragma unroll
  for (int kt = 0; kt < 8; kt++) {
    half4 o;
#pragma unroll
    for (int j = 0; j < 4; j++) o[j] = (_Float16)(st[kt][j] * inv);
    *(half4*)(Pl + swz(qi, 16 * kt + 4 * g)) = o;
  }

  __syncthreads();   // covers Vt staging + Pl writes

  // ---- O = P·V
  f32x4 acc[4];
#pragma unroll
  for (int dt = 0; dt < 4; dt++) acc[dt] = (f32x4){0.f, 0.f, 0.f, 0.f};
  half8 ap[4];
#pragma unroll
  for (int ks = 0; ks < 4; ks++)
    ap[ks] = *(const half8*)(Pl + swz(16 * w + fr, 32 * ks + 8 * g));
#pragma unroll
  for (int dt = 0; dt < 4; dt++)
#pragma unroll
    for (int ks = 0; ks < 4; ks++) {
      half8 bv = *(const half8*)(Vt + swz(16 * dt + fr, 32 * ks + 8 * g));
      acc[dt] = __builtin_amdgcn_mfma_f32_16x16x32_f16(ap[ks], bv, acc[dt], 0, 0, 0);
    }

#pragma unroll
  for (int dt = 0; dt < 4; dt++)
#pragma unroll
    for (int j = 0; j < 4; j++) {
      int q = q0 + 16 * w + 4 * g + j;
      attn_out[(size_t)(b * S_SZ + q) * DIMM + h * HDIM + 16 * dt + fr] = (_Float16)acc[dt][j];
    }
}

// ---------- launch ----------
extern "C" void kernel_launch(void* const* d_in, const int* in_sizes, int n_in,
                              void* d_out, int out_size, void* d_ws, size_t ws_size,
                              hipStream_t stream) {
  const float* x    = (const float*)d_in[0];
  const float* Wqkv = (const float*)d_in[1];
  const float* Wout = (const float*)d_in[2];

  char* ws = (char*)d_ws;
  _Float16* xb    = (_Float16*)(ws);                 // 4096*512  f16 =  4 MB
  _Float16* WqkvT = (_Float16*)(ws + 4194304);       // 1536*512  f16 = 1.5 MB
  _Float16* WoutT = (_Float16*)(ws + 5767168);       //  512*512  f16 = 0.5 MB
  _Float16* qkv   = (_Float16*)(ws + 6291456);       // 4096*1536 f16 = 12 MB
  _Float16* attn  = (_Float16*)(ws + 18874368);      // 4096*512  f16 =  4 MB

  convert_f32_f16<<<2048, 256, 0, stream>>>(x, xb, MROWS * DIMM);
  transpose_to_f16<<<dim3(48, 16), 256, 0, stream>>>(Wqkv, WqkvT, DIMM, NQKV);
  transpose_to_f16<<<dim3(16, 16), 256, 0, stream>>>(Wout, WoutT, DIMM, DIMM);

  gemm_f16<true><<<dim3(12, 32), 256, 0, stream>>>(xb, WqkvT, (void*)qkv, MROWS, NQKV, DIMM);
  attn_mfma<<<dim3(32, NH, 2), 256, 0, stream>>>(qkv, attn);
  gemm_f16<false><<<dim3(4, 32), 256, 0, stream>>>(attn, WoutT, d_out, MROWS, DIMM, DIMM);
}

// Round 11
// 107.572 us; speedup vs baseline: 1.5896x; 1.0319x over previous
//
#include <hip/hip_runtime.h>

// Sliding-window attention: x@Wqkv -> SWA(win=64, zero-pad in softmax) -> @Wout
// B=2 S=2048 DIM=512 H=8 HD=64. All GEMMs + attention in f16 MFMA.
// R8: GEMM staging via global_load_lds width-16 (m97 structure, linear LDS).
// R10: 3 prep kernels fused into 1 grid-partitioned dispatch (6 -> 4 dispatches).

#define S_SZ   2048
#define DIMM   512
#define NH     8
#define HDIM   64
#define MROWS  4096      // B*S
#define NQKV   1536      // 3*DIM

typedef _Float16 half8 __attribute__((ext_vector_type(8)));
typedef _Float16 half4 __attribute__((ext_vector_type(4)));
typedef float    f32x4 __attribute__((ext_vector_type(4)));

// async global->LDS, 16B per lane; LDS dest is wave-uniform base + lane*16
#define GLOAD16(g, l)                                                          \
  __builtin_amdgcn_global_load_lds(                                            \
      (const __attribute__((address_space(1))) void*)(g),                      \
      (__attribute__((address_space(3))) void*)(l), 16, 0, 0)

// ---------- fused prep: convert x (f32->f16) + transpose both weights ----------
// blocks [0,2048): xb = f16(x)            (2M elems, 4/thread)
// blocks [2048,2816): WqkvT[n][k]         (f32 [512][1536] -> f16 [1536][512])
// blocks [2816,3072): WoutT[n][k]         (f32 [512][512]  -> f16 [512][512])
__global__ __launch_bounds__(256) void prep_fused(const float* __restrict__ x,
                                                  const float* __restrict__ Wqkv,
                                                  const float* __restrict__ Wout,
                                                  _Float16* __restrict__ xb,
                                                  _Float16* __restrict__ WqkvT,
                                                  _Float16* __restrict__ WoutT) {
  __shared__ float tile[32][33];
  const int blk = blockIdx.x;
  if (blk < 2048) {
    int i = (blk * 256 + threadIdx.x) * 4;
    float4 v = *reinterpret_cast<const float4*>(x + i);
    half4 h;
    h[0] = (_Float16)v.x; h[1] = (_Float16)v.y; h[2] = (_Float16)v.z; h[3] = (_Float16)v.w;
    *reinterpret_cast<half4*>(xb + i) = h;
    return;
  }
  const float* in;  _Float16* out;  int K, N, bx, by;
  if (blk < 2816) { in = Wqkv; out = WqkvT; K = 512; N = 1536; int r = blk - 2048; bx = r % 48; by = r / 48; }
  else            { in = Wout; out = WoutT; K = 512; N = 512;  int r = blk - 2816; bx = r % 16; by = r / 16; }
  const int n0 = bx * 32, k0 = by * 32;
  const int tx = threadIdx.x & 31, ty = threadIdx.x >> 5;   // 32 x 8
#pragma unroll
  for (int i = 0; i < 4; i++) {
    int k = ty + i * 8;
    tile[k][tx] = in[(size_t)(k0 + k) * N + n0 + tx];
  }
  __syncthreads();
#pragma unroll
  for (int i = 0; i < 4; i++) {
    int n = ty + i * 8;
    out[(size_t)(n0 + n) * K + k0 + tx] = (_Float16)tile[tx][n];
  }
}

// ---------- GEMM: C[M][N] = A[M][K] * BT[N][K]^T, f16, MFMA 16x16x32 ----------
// 128x128 tile, BK=32, 4 waves (2x2), 64x64/wave. Staging: global_load_lds w16,
// linear LDS LDA=32 (m97 structure). Wave w stages rows 32w..32w+31 of A and BT
// as 2 chunks x 1KB (16 rows each); lane l -> row (l>>2), col-halfs (l&3)*8.
template <bool C_F16>
__global__ __launch_bounds__(256) void gemm_f16(const _Float16* __restrict__ A,
                                                const _Float16* __restrict__ BT,
                                                void* __restrict__ C,
                                                int M, int N, int K) {
  __shared__ _Float16 As[128 * 32];
  __shared__ _Float16 Bs[128 * 32];

  const int brow = blockIdx.y * 128, bcol = blockIdx.x * 128;
  const int tid = threadIdx.x;
  const int lane = tid & 63, wid = tid >> 6;
  const int wm = (wid >> 1) * 64, wn = (wid & 1) * 64;

  f32x4 acc[4][4] = {};

  const int srow = wid * 32 + (lane >> 2);   // staged row (chunk 0); chunk 1 = +16
  const int scol = (lane & 3) * 8;           // staged col (halfs)
  _Float16* lA = As + wid * 1024;            // wave-uniform chunk bases (halfs)
  _Float16* lB = Bs + wid * 1024;

  const int fr = lane & 15, kb = (lane >> 4) * 8;

  for (int kt = 0; kt < K; kt += 32) {
    const _Float16* ga = A  + (size_t)(brow + srow) * K + kt + scol;
    const _Float16* gb = BT + (size_t)(bcol + srow) * K + kt + scol;
    GLOAD16(ga, lA);
    GLOAD16(ga + (size_t)16 * K, lA + 512);
    GLOAD16(gb, lB);
    GLOAD16(gb + (size_t)16 * K, lB + 512);
    __syncthreads();   // drains vmcnt (gload) for all waves

    half8 af[4], bf[4];
#pragma unroll
    for (int m = 0; m < 4; m++) af[m] = *(const half8*)(As + (wm + m * 16 + fr) * 32 + kb);
#pragma unroll
    for (int n = 0; n < 4; n++) bf[n] = *(const half8*)(Bs + (wn + n * 16 + fr) * 32 + kb);
#pragma unroll
    for (int m = 0; m < 4; m++)
#pragma unroll
      for (int n = 0; n < 4; n++)
        acc[m][n] = __builtin_amdgcn_mfma_f32_16x16x32_f16(af[m], bf[n], acc[m][n], 0, 0, 0);
    __syncthreads();   // frag reads done before next iter's staging overwrites
  }

  // C/D layout: col = lane&15, row = (lane>>4)*4 + j   [verified m89/m91]
  const int fq = lane >> 4;
#pragma unroll
  for (int m = 0; m < 4; m++)
#pragma unroll
    for (int n = 0; n < 4; n++)
#pragma unroll
      for (int j = 0; j < 4; j++) {
        int rr = brow + wm + m * 16 + fq * 4 + j;
        int cc = bcol + wn + n * 16 + fr;
        if (C_F16) ((_Float16*)C)[(size_t)rr * N + cc] = (_Float16)acc[m][n][j];
        else       ((float*)C)[(size_t)rr * N + cc]    = acc[m][n][j];
      }
}

// ---------- MFMA sliding-window attention ----------
// Block = (64 queries) x head x batch, 4 waves; wave w owns queries 16w..16w+15.
// S^T = K·Q^T per wave; softmax in-register (band-masked, shfl_xor 16/32 reduce);
// P (f16) + V^T staged in XOR-swizzled LDS; O = P·V.
// OOB keys -> zero rows -> score 0 kept in softmax (matches reference zero-pad).
__device__ __forceinline__ int swz(int row, int colh) {
  int key = ((row & 7) ^ ((row >> 3) & 7)) << 4;
  return row * 128 + (((colh * 2) ^ key) >> 1);
}

__global__ __launch_bounds__(256) void attn_mfma(const _Float16* __restrict__ qkv,
                                                 _Float16* __restrict__ attn_out) {
  __shared__ _Float16 Vt[64 * 128];   // V^T: [dim][key], swizzled
  __shared__ _Float16 Pl[64 * 128];   // P:   [query][key], swizzled

  const int b = blockIdx.z, h = blockIdx.y, q0 = blockIdx.x * 64;
  const int kv0 = q0 - 32;
  const int tid = threadIdx.x;
  const int lane = tid & 63, w = tid >> 6;
  const int fr = lane & 15, g = lane >> 4;

  // ---- stage V^T
  {
    const int jg = tid >> 3, dg = tid & 7;
    half8 vv[4];
#pragma unroll
    for (int i = 0; i < 4; i++) {
      int s = kv0 + jg * 4 + i;
      half8 z = {};
      if (s >= 0 && s < S_SZ)
        z = *(const half8*)(qkv + (size_t)(b * S_SZ + s) * NQKV + 2 * DIMM + h * HDIM + dg * 8);
      vv[i] = z;
    }
#pragma unroll
    for (int i2 = 0; i2 < 8; i2++) {
      half4 o;
      o[0] = vv[0][i2]; o[1] = vv[1][i2]; o[2] = vv[2][i2]; o[3] = vv[3][i2];
      *(half4*)(Vt + swz(dg * 8 + i2, jg * 4)) = o;
    }
  }

  // ---- S^T = K·Q^T
  const _Float16* qbase = qkv + (size_t)(b * S_SZ + q0 + 16 * w + fr) * NQKV + h * HDIM;
  half8 bq0 = *(const half8*)(qbase + 8 * g);
  half8 bq1 = *(const half8*)(qbase + 32 + 8 * g);

  f32x4 st[8];
#pragma unroll
  for (int kt = 0; kt < 8; kt++) st[kt] = (f32x4){0.f, 0.f, 0.f, 0.f};

#pragma unroll
  for (int kt = 0; kt < 8; kt++) {
    int s = kv0 + 16 * kt + fr;
    half8 a0 = {}, a1 = {};
    if (s >= 0 && s < S_SZ) {
      const _Float16* kb2 = qkv + (size_t)(b * S_SZ + s) * NQKV + DIMM + h * HDIM;
      a0 = *(const half8*)(kb2 + 8 * g);
      a1 = *(const half8*)(kb2 + 32 + 8 * g);
    }
    st[kt] = __builtin_amdgcn_mfma_f32_16x16x32_f16(a0, bq0, st[kt], 0, 0, 0);
    st[kt] = __builtin_amdgcn_mfma_f32_16x16x32_f16(a1, bq1, st[kt], 0, 0, 0);
  }

  // ---- softmax over band [qi, qi+63]
  const int qi = 16 * w + fr;
  float m = -1e30f;
#pragma unroll
  for (int kt = 0; kt < 8; kt++)
#pragma unroll
    for (int j = 0; j < 4; j++) {
      int krel = 16 * kt + 4 * g + j;
      float scv = st[kt][j] * 0.125f;
      st[kt][j] = scv;
      if (krel >= qi && krel < qi + 64) m = fmaxf(m, scv);
    }
  m = fmaxf(m, __shfl_xor(m, 16));
  m = fmaxf(m, __shfl_xor(m, 32));
  float sum = 0.f;
#pragma unroll
  for (int kt = 0; kt < 8; kt++)
#pragma unroll
    for (int j = 0; j < 4; j++) {
      int krel = 16 * kt + 4 * g + j;
      float p = (krel >= qi && krel < qi + 64) ? __expf(st[kt][j] - m) : 0.f;
      st[kt][j] = p;
      sum += p;
    }
  sum += __shfl_xor(sum, 16);
  sum += __shfl_xor(sum, 32);
  const float inv = 1.f / sum;
#pragma unroll
  for (int kt = 0; kt < 8; kt++) {
    half4 o;
#pragma unroll
    for (int j = 0; j < 4; j++) o[j] = (_Float16)(st[kt][j] * inv);
    *(half4*)(Pl + swz(qi, 16 * kt + 4 * g)) = o;
  }

  __syncthreads();   // covers Vt staging + Pl writes

  // ---- O = P·V
  f32x4 acc[4];
#pragma unroll
  for (int dt = 0; dt < 4; dt++) acc[dt] = (f32x4){0.f, 0.f, 0.f, 0.f};
  half8 ap[4];
#pragma unroll
  for (int ks = 0; ks < 4; ks++)
    ap[ks] = *(const half8*)(Pl + swz(16 * w + fr, 32 * ks + 8 * g));
#pragma unroll
  for (int dt = 0; dt < 4; dt++)
#pragma unroll
    for (int ks = 0; ks < 4; ks++) {
      half8 bv = *(const half8*)(Vt + swz(16 * dt + fr, 32 * ks + 8 * g));
      acc[dt] = __builtin_amdgcn_mfma_f32_16x16x32_f16(ap[ks], bv, acc[dt], 0, 0, 0);
    }

#pragma unroll
  for (int dt = 0; dt < 4; dt++)
#pragma unroll
    for (int j = 0; j < 4; j++) {
      int q = q0 + 16 * w + 4 * g + j;
      attn_out[(size_t)(b * S_SZ + q) * DIMM + h * HDIM + 16 * dt + fr] = (_Float16)acc[dt][j];
    }
}

// ---------- launch ----------
extern "C" void kernel_launch(void* const* d_in, const int* in_sizes, int n_in,
                              void* d_out, int out_size, void* d_ws, size_t ws_size,
                              hipStream_t stream) {
  const float* x    = (const float*)d_in[0];
  const float* Wqkv = (const float*)d_in[1];
  const float* Wout = (const float*)d_in[2];

  char* ws = (char*)d_ws;
  _Float16* xb    = (_Float16*)(ws);                 // 4096*512  f16 =  4 MB
  _Float16* WqkvT = (_Float16*)(ws + 4194304);       // 1536*512  f16 = 1.5 MB
  _Float16* WoutT = (_Float16*)(ws + 5767168);       //  512*512  f16 = 0.5 MB
  _Float16* qkv   = (_Float16*)(ws + 6291456);       // 4096*1536 f16 = 12 MB
  _Float16* attn  = (_Float16*)(ws + 18874368);      // 4096*512  f16 =  4 MB

  prep_fused<<<3072, 256, 0, stream>>>(x, Wqkv, Wout, xb, WqkvT, WoutT);
  gemm_f16<true><<<dim3(12, 32), 256, 0, stream>>>(xb, WqkvT, (void*)qkv, MROWS, NQKV, DIMM);
  attn_mfma<<<dim3(32, NH, 2), 256, 0, stream>>>(qkv, attn);
  gemm_f16<false><<<dim3(4, 32), 256, 0, stream>>>(attn, WoutT, d_out, MROWS, DIMM, DIMM);
}

// Round 12
// 103.381 us; speedup vs baseline: 1.6540x; 1.0405x over previous
//
#include <hip/hip_runtime.h>

// Sliding-window attention: x@Wqkv -> SWA(win=64, zero-pad in softmax) -> @Wout
// B=2 S=2048 DIM=512 H=8 HD=64. All GEMMs + attention in f16 MFMA.
// R8:  GEMM staging via global_load_lds width-16.
// R10: 3 prep kernels fused into 1 grid-partitioned dispatch.
// R11: GEMM 2-phase pipeline (dbuf LDS, stage-before-compute, 1 barrier/iter);
//      attn stages K in swizzled LDS (kills 4x redundant strided K loads).

#define S_SZ   2048
#define DIMM   512
#define NH     8
#define HDIM   64
#define MROWS  4096      // B*S
#define NQKV   1536      // 3*DIM

typedef _Float16 half8 __attribute__((ext_vector_type(8)));
typedef _Float16 half4 __attribute__((ext_vector_type(4)));
typedef float    f32x4 __attribute__((ext_vector_type(4)));

// async global->LDS, 16B per lane; LDS dest is wave-uniform base + lane*16
#define GLOAD16(g, l)                                                          \
  __builtin_amdgcn_global_load_lds(                                            \
      (const __attribute__((address_space(1))) void*)(g),                      \
      (__attribute__((address_space(3))) void*)(l), 16, 0, 0)

// ---------- fused prep: convert x (f32->f16) + transpose both weights ----------
__global__ __launch_bounds__(256) void prep_fused(const float* __restrict__ x,
                                                  const float* __restrict__ Wqkv,
                                                  const float* __restrict__ Wout,
                                                  _Float16* __restrict__ xb,
                                                  _Float16* __restrict__ WqkvT,
                                                  _Float16* __restrict__ WoutT) {
  __shared__ float tile[32][33];
  const int blk = blockIdx.x;
  if (blk < 2048) {
    int i = (blk * 256 + threadIdx.x) * 4;
    float4 v = *reinterpret_cast<const float4*>(x + i);
    half4 h;
    h[0] = (_Float16)v.x; h[1] = (_Float16)v.y; h[2] = (_Float16)v.z; h[3] = (_Float16)v.w;
    *reinterpret_cast<half4*>(xb + i) = h;
    return;
  }
  const float* in;  _Float16* out;  int K, N, bx, by;
  if (blk < 2816) { in = Wqkv; out = WqkvT; K = 512; N = 1536; int r = blk - 2048; bx = r % 48; by = r / 48; }
  else            { in = Wout; out = WoutT; K = 512; N = 512;  int r = blk - 2816; bx = r % 16; by = r / 16; }
  const int n0 = bx * 32, k0 = by * 32;
  const int tx = threadIdx.x & 31, ty = threadIdx.x >> 5;   // 32 x 8
#pragma unroll
  for (int i = 0; i < 4; i++) {
    int k = ty + i * 8;
    tile[k][tx] = in[(size_t)(k0 + k) * N + n0 + tx];
  }
  __syncthreads();
#pragma unroll
  for (int i = 0; i < 4; i++) {
    int n = ty + i * 8;
    out[(size_t)(n0 + n) * K + k0 + tx] = (_Float16)tile[tx][n];
  }
}

// ---------- GEMM: C[M][N] = A[M][K] * BT[N][K]^T, f16, MFMA 16x16x32 ----------
// 128x128 tile, BK=32, 4 waves (2x2). 2-phase pipeline: double-buffered LDS,
// next tile's global_load_lds issued BEFORE current tile's MFMAs, single
// __syncthreads()/iter (drains the async loads + fences frag reads).
template <bool C_F16>
__global__ __launch_bounds__(256) void gemm_f16(const _Float16* __restrict__ A,
                                                const _Float16* __restrict__ BT,
                                                void* __restrict__ C,
                                                int M, int N, int K) {
  __shared__ _Float16 As[2][128 * 32];
  __shared__ _Float16 Bs[2][128 * 32];

  const int brow = blockIdx.y * 128, bcol = blockIdx.x * 128;
  const int tid = threadIdx.x;
  const int lane = tid & 63, wid = tid >> 6;
  const int wm = (wid >> 1) * 64, wn = (wid & 1) * 64;

  f32x4 acc[4][4] = {};

  const int srow = wid * 32 + (lane >> 2);   // staged row (chunk 0); chunk 1 = +16
  const int scol = (lane & 3) * 8;           // staged col (halfs)
  const int fr = lane & 15, kb = (lane >> 4) * 8;

  const _Float16* gaBase = A  + (size_t)(brow + srow) * K + scol;
  const _Float16* gbBase = BT + (size_t)(bcol + srow) * K + scol;

#define STAGE(buf, kt)                                                         \
  do {                                                                         \
    const _Float16* ga = gaBase + (kt);                                        \
    const _Float16* gb = gbBase + (kt);                                        \
    _Float16* lA = As[buf] + wid * 1024;                                       \
    _Float16* lB = Bs[buf] + wid * 1024;                                       \
    GLOAD16(ga, lA);                                                           \
    GLOAD16(ga + (size_t)16 * K, lA + 512);                                    \
    GLOAD16(gb, lB);                                                           \
    GLOAD16(gb + (size_t)16 * K, lB + 512);                                    \
  } while (0)

  STAGE(0, 0);
  __syncthreads();

  const int NT = K >> 5;
  int cur = 0;
  for (int t = 0; t < NT; t++) {
    if (t + 1 < NT) STAGE(cur ^ 1, (t + 1) * 32);   // async prefetch next tile

    half8 af[4], bf[4];
#pragma unroll
    for (int m = 0; m < 4; m++) af[m] = *(const half8*)(As[cur] + (wm + m * 16 + fr) * 32 + kb);
#pragma unroll
    for (int n = 0; n < 4; n++) bf[n] = *(const half8*)(Bs[cur] + (wn + n * 16 + fr) * 32 + kb);
#pragma unroll
    for (int m = 0; m < 4; m++)
#pragma unroll
      for (int n = 0; n < 4; n++)
        acc[m][n] = __builtin_amdgcn_mfma_f32_16x16x32_f16(af[m], bf[n], acc[m][n], 0, 0, 0);

    __syncthreads();   // drains prefetch vmcnt + fences this buf's frag reads
    cur ^= 1;
  }
#undef STAGE

  // C/D layout: col = lane&15, row = (lane>>4)*4 + j   [verified m89/m91]
  const int fq = lane >> 4;
#pragma unroll
  for (int m = 0; m < 4; m++)
#pragma unroll
    for (int n = 0; n < 4; n++)
#pragma unroll
      for (int j = 0; j < 4; j++) {
        int rr = brow + wm + m * 16 + fq * 4 + j;
        int cc = bcol + wn + n * 16 + fr;
        if (C_F16) ((_Float16*)C)[(size_t)rr * N + cc] = (_Float16)acc[m][n][j];
        else       ((float*)C)[(size_t)rr * N + cc]    = acc[m][n][j];
      }
}

// ---------- MFMA sliding-window attention ----------
// Block = (64 queries) x head x batch, 4 waves; wave w owns queries 16w..16w+15.
// R11: K staged once per block in XOR-swizzled LDS (all 4 waves read the SAME
// 128-key tile; was 4x redundant strided global loads). S^T = K·Q^T; softmax
// in-register (band-masked, shfl_xor 16/32); P via LDS (wave-private rows, no
// barrier); O = P·V from swizzled Vt. OOB keys staged as zeros -> score 0 kept
// in softmax (matches reference zero-pad).
__device__ __forceinline__ int swz(int row, int colh) {
  int key = ((row & 7) ^ ((row >> 3) & 7)) << 4;
  return row * 128 + (((colh * 2) ^ key) >> 1);
}

__global__ __launch_bounds__(256) void attn_mfma(const _Float16* __restrict__ qkv,
                                                 _Float16* __restrict__ attn_out) {
  __shared__ _Float16 Vt[64 * 128];   // V^T: [dim][key], swizzled
  __shared__ _Float16 Pl[64 * 128];   // P:   [query][key], swizzled
  __shared__ _Float16 Ks[128 * 64];   // K:   [key][dim], slot = dimg ^ (key&7)

  const int b = blockIdx.z, h = blockIdx.y, q0 = blockIdx.x * 64;
  const int kv0 = q0 - 32;
  const int tid = threadIdx.x;
  const int lane = tid & 63, w = tid >> 6;
  const int fr = lane & 15, g = lane >> 4;

  // ---- stage V^T (transposed via registers) and K (row-major, swizzled slots)
  {
    const int jg = tid >> 3, dg = tid & 7;
    half8 vv[4];
#pragma unroll
    for (int i = 0; i < 4; i++) {
      int s = kv0 + jg * 4 + i;
      half8 z = {};
      if (s >= 0 && s < S_SZ)
        z = *(const half8*)(qkv + (size_t)(b * S_SZ + s) * NQKV + 2 * DIMM + h * HDIM + dg * 8);
      vv[i] = z;
    }
#pragma unroll
    for (int i2 = 0; i2 < 8; i2++) {
      half4 o;
      o[0] = vv[0][i2]; o[1] = vv[1][i2]; o[2] = vv[2][i2]; o[3] = vv[3][i2];
      *(half4*)(Vt + swz(dg * 8 + i2, jg * 4)) = o;
    }
    const int k0r = tid >> 3;            // 0..31
#pragma unroll
    for (int i = 0; i < 4; i++) {
      int key = k0r + i * 32;
      int s = kv0 + key;
      half8 z = {};
      if (s >= 0 && s < S_SZ)
        z = *(const half8*)(qkv + (size_t)(b * S_SZ + s) * NQKV + DIMM + h * HDIM + dg * 8);
      int slot = dg ^ (key & 7);
      *(half8*)(Ks + key * 64 + slot * 8) = z;
    }
  }

  // ---- Q fragments (per-wave, direct from global; small)
  const _Float16* qbase = qkv + (size_t)(b * S_SZ + q0 + 16 * w + fr) * NQKV + h * HDIM;
  half8 bq0 = *(const half8*)(qbase + 8 * g);        // dims  8g..+7
  half8 bq1 = *(const half8*)(qbase + 32 + 8 * g);   // dims 32+8g..+7

  __syncthreads();   // Ks + Vt staged

  // ---- S^T = K·Q^T from LDS
  f32x4 st[8];
#pragma unroll
  for (int kt = 0; kt < 8; kt++) st[kt] = (f32x4){0.f, 0.f, 0.f, 0.f};
#pragma unroll
  for (int kt = 0; kt < 8; kt++) {
    const int key = 16 * kt + fr;
    const int s0 = g ^ (key & 7), s1 = (g + 4) ^ (key & 7);
    half8 a0 = *(const half8*)(Ks + key * 64 + s0 * 8);
    half8 a1 = *(const half8*)(Ks + key * 64 + s1 * 8);
    st[kt] = __builtin_amdgcn_mfma_f32_16x16x32_f16(a0, bq0, st[kt], 0, 0, 0);
    st[kt] = __builtin_amdgcn_mfma_f32_16x16x32_f16(a1, bq1, st[kt], 0, 0, 0);
  }

  // ---- softmax over band [qi, qi+63]; lane's keys: 16kt+4g+j, query col = qi
  const int qi = 16 * w + fr;
  float m = -1e30f;
#pragma unroll
  for (int kt = 0; kt < 8; kt++)
#pragma unroll
    for (int j = 0; j < 4; j++) {
      int krel = 16 * kt + 4 * g + j;
      float scv = st[kt][j] * 0.125f;   // 1/sqrt(64)
      st[kt][j] = scv;
      if (krel >= qi && krel < qi + 64) m = fmaxf(m, scv);
    }
  m = fmaxf(m, __shfl_xor(m, 16));
  m = fmaxf(m, __shfl_xor(m, 32));
  float sum = 0.f;
#pragma unroll
  for (int kt = 0; kt < 8; kt++)
#pragma unroll
    for (int j = 0; j < 4; j++) {
      int krel = 16 * kt + 4 * g + j;
      float p = (krel >= qi && krel < qi + 64) ? __expf(st[kt][j] - m) : 0.f;
      st[kt][j] = p;
      sum += p;
    }
  sum += __shfl_xor(sum, 16);
  sum += __shfl_xor(sum, 32);
  const float inv = 1.f / sum;
#pragma unroll
  for (int kt = 0; kt < 8; kt++) {
    half4 o;
#pragma unroll
    for (int j = 0; j < 4; j++) o[j] = (_Float16)(st[kt][j] * inv);
    *(half4*)(Pl + swz(qi, 16 * kt + 4 * g)) = o;
  }
  // no barrier: Pl rows are wave-private (wave w writes/reads rows 16w..16w+15)

  // ---- O = P·V
  f32x4 acc[4];
#pragma unroll
  for (int dt = 0; dt < 4; dt++) acc[dt] = (f32x4){0.f, 0.f, 0.f, 0.f};
  half8 ap[4];
#pragma unroll
  for (int ks = 0; ks < 4; ks++)
    ap[ks] = *(const half8*)(Pl + swz(16 * w + fr, 32 * ks + 8 * g));
#pragma unroll
  for (int dt = 0; dt < 4; dt++)
#pragma unroll
    for (int ks = 0; ks < 4; ks++) {
      half8 bv = *(const half8*)(Vt + swz(16 * dt + fr, 32 * ks + 8 * g));
      acc[dt] = __builtin_amdgcn_mfma_f32_16x16x32_f16(ap[ks], bv, acc[dt], 0, 0, 0);
    }

#pragma unroll
  for (int dt = 0; dt < 4; dt++)
#pragma unroll
    for (int j = 0; j < 4; j++) {
      int q = q0 + 16 * w + 4 * g + j;
      attn_out[(size_t)(b * S_SZ + q) * DIMM + h * HDIM + 16 * dt + fr] = (_Float16)acc[dt][j];
    }
}

// ---------- launch ----------
extern "C" void kernel_launch(void* const* d_in, const int* in_sizes, int n_in,
                              void* d_out, int out_size, void* d_ws, size_t ws_size,
                              hipStream_t stream) {
  const float* x    = (const float*)d_in[0];
  const float* Wqkv = (const float*)d_in[1];
  const float* Wout = (const float*)d_in[2];

  char* ws = (char*)d_ws;
  _Float16* xb    = (_Float16*)(ws);                 // 4096*512  f16 =  4 MB
  _Float16* WqkvT = (_Float16*)(ws + 4194304);       // 1536*512  f16 = 1.5 MB
  _Float16* WoutT = (_Float16*)(ws + 5767168);       //  512*512  f16 = 0.5 MB
  _Float16* qkv   = (_Float16*)(ws + 6291456);       // 4096*1536 f16 = 12 MB
  _Float16* attn  = (_Float16*)(ws + 18874368);      // 4096*512  f16 =  4 MB

  prep_fused<<<3072, 256, 0, stream>>>(x, Wqkv, Wout, xb, WqkvT, WoutT);
  gemm_f16<true><<<dim3(12, 32), 256, 0, stream>>>(xb, WqkvT, (void*)qkv, MROWS, NQKV, DIMM);
  attn_mfma<<<dim3(32, NH, 2), 256, 0, stream>>>(qkv, attn);
  gemm_f16<false><<<dim3(4, 32), 256, 0, stream>>>(attn, WoutT, d_out, MROWS, DIMM, DIMM);
}

// Round 16
// 101.250 us; speedup vs baseline: 1.6888x; 1.0210x over previous
//
#include <hip/hip_runtime.h>

// Sliding-window attention: x@Wqkv -> SWA(win=64, zero-pad in softmax) -> @Wout
// B=2 S=2048 DIM=512 H=8 HD=64. All GEMMs + attention in f16 MFMA.
// R8:  GEMM staging via global_load_lds width-16.
// R10: 3 prep kernels fused into 1 grid-partitioned dispatch.
// R11: GEMM 2-phase pipeline (dbuf LDS, 1 barrier/iter); attn K staged in LDS.
// R12: gemm2 BM=64 tile -> 256 blocks (was 128; half the CUs sat idle).

#define S_SZ   2048
#define DIMM   512
#define NH     8
#define HDIM   64
#define MROWS  4096      // B*S
#define NQKV   1536      // 3*DIM

typedef _Float16 half8 __attribute__((ext_vector_type(8)));
typedef _Float16 half4 __attribute__((ext_vector_type(4)));
typedef float    f32x4 __attribute__((ext_vector_type(4)));

// async global->LDS, 16B per lane; LDS dest is wave-uniform base + lane*16
#define GLOAD16(g, l)                                                          \
  __builtin_amdgcn_global_load_lds(                                            \
      (const __attribute__((address_space(1))) void*)(g),                      \
      (__attribute__((address_space(3))) void*)(l), 16, 0, 0)

// ---------- fused prep: convert x (f32->f16) + transpose both weights ----------
__global__ __launch_bounds__(256) void prep_fused(const float* __restrict__ x,
                                                  const float* __restrict__ Wqkv,
                                                  const float* __restrict__ Wout,
                                                  _Float16* __restrict__ xb,
                                                  _Float16* __restrict__ WqkvT,
                                                  _Float16* __restrict__ WoutT) {
  __shared__ float tile[32][33];
  const int blk = blockIdx.x;
  if (blk < 2048) {
    int i = (blk * 256 + threadIdx.x) * 4;
    float4 v = *reinterpret_cast<const float4*>(x + i);
    half4 h;
    h[0] = (_Float16)v.x; h[1] = (_Float16)v.y; h[2] = (_Float16)v.z; h[3] = (_Float16)v.w;
    *reinterpret_cast<half4*>(xb + i) = h;
    return;
  }
  const float* in;  _Float16* out;  int K, N, bx, by;
  if (blk < 2816) { in = Wqkv; out = WqkvT; K = 512; N = 1536; int r = blk - 2048; bx = r % 48; by = r / 48; }
  else            { in = Wout; out = WoutT; K = 512; N = 512;  int r = blk - 2816; bx = r % 16; by = r / 16; }
  const int n0 = bx * 32, k0 = by * 32;
  const int tx = threadIdx.x & 31, ty = threadIdx.x >> 5;   // 32 x 8
#pragma unroll
  for (int i = 0; i < 4; i++) {
    int k = ty + i * 8;
    tile[k][tx] = in[(size_t)(k0 + k) * N + n0 + tx];
  }
  __syncthreads();
#pragma unroll
  for (int i = 0; i < 4; i++) {
    int n = ty + i * 8;
    out[(size_t)(n0 + n) * K + k0 + tx] = (_Float16)tile[tx][n];
  }
}

// ---------- GEMM: C[M][N] = A[M][K] * BT[N][K]^T, f16, MFMA 16x16x32 ----------
// BMx128 tile (BM=128 or 64), BK=32, 4 waves (2x2). 2-phase pipeline:
// double-buffered LDS, next tile's global_load_lds issued BEFORE current tile's
// MFMAs, single __syncthreads()/iter.
template <int BM, bool C_F16>
__global__ __launch_bounds__(256) void gemm_f16(const _Float16* __restrict__ A,
                                                const _Float16* __restrict__ BT,
                                                void* __restrict__ C,
                                                int M, int N, int K) {
  __shared__ _Float16 As[2][BM * 32];
  __shared__ _Float16 Bs[2][128 * 32];
  constexpr int MR = BM / 32;   // m-fragments per wave (4 or 2)

  const int brow = blockIdx.y * BM, bcol = blockIdx.x * 128;
  const int tid = threadIdx.x;
  const int lane = tid & 63, wid = tid >> 6;
  const int wm = (wid >> 1) * (BM / 2), wn = (wid & 1) * 64;

  f32x4 acc[MR][4] = {};

  // staging: B = wave w rows 32w..+31 (2 chunks); A = 32 rows (BM=128) or 16 (BM=64)
  const int srowB = wid * 32 + (lane >> 2);
  const int srowA = (BM == 128) ? srowB : (wid * 16 + (lane >> 2));
  const int scol  = (lane & 3) * 8;
  const int fr = lane & 15, kb = (lane >> 4) * 8;

  const _Float16* gaBase = A  + (size_t)(brow + srowA) * K + scol;
  const _Float16* gbBase = BT + (size_t)(bcol + srowB) * K + scol;

#define STAGE(buf, kt)                                                         \
  do {                                                                         \
    const _Float16* ga = gaBase + (kt);                                        \
    const _Float16* gb = gbBase + (kt);                                        \
    _Float16* lA = As[buf] + wid * (BM == 128 ? 1024 : 512);                   \
    _Float16* lB = Bs[buf] + wid * 1024;                                       \
    GLOAD16(ga, lA);                                                           \
    if constexpr (BM == 128) GLOAD16(ga + (size_t)16 * K, lA + 512);           \
    GLOAD16(gb, lB);                                                           \
    GLOAD16(gb + (size_t)16 * K, lB + 512);                                    \
  } while (0)

  STAGE(0, 0);
  __syncthreads();

  const int NT = K >> 5;
  int cur = 0;
  for (int t = 0; t < NT; t++) {
    if (t + 1 < NT) STAGE(cur ^ 1, (t + 1) * 32);   // async prefetch next tile

    half8 af[MR], bf[4];
#pragma unroll
    for (int m = 0; m < MR; m++) af[m] = *(const half8*)(As[cur] + (wm + m * 16 + fr) * 32 + kb);
#pragma unroll
    for (int n = 0; n < 4; n++)  bf[n] = *(const half8*)(Bs[cur] + (wn + n * 16 + fr) * 32 + kb);
#pragma unroll
    for (int m = 0; m < MR; m++)
#pragma unroll
      for (int n = 0; n < 4; n++)
        acc[m][n] = __builtin_amdgcn_mfma_f32_16x16x32_f16(af[m], bf[n], acc[m][n], 0, 0, 0);

    __syncthreads();   // drains prefetch vmcnt + fences this buf's frag reads
    cur ^= 1;
  }
#undef STAGE

  // C/D layout: col = lane&15, row = (lane>>4)*4 + j   [verified m89/m91]
  const int fq = lane >> 4;
#pragma unroll
  for (int m = 0; m < MR; m++)
#pragma unroll
    for (int n = 0; n < 4; n++)
#pragma unroll
      for (int j = 0; j < 4; j++) {
        int rr = brow + wm + m * 16 + fq * 4 + j;
        int cc = bcol + wn + n * 16 + fr;
        if (C_F16) ((_Float16*)C)[(size_t)rr * N + cc] = (_Float16)acc[m][n][j];
        else       ((float*)C)[(size_t)rr * N + cc]    = acc[m][n][j];
      }
}

// ---------- MFMA sliding-window attention ----------
// Block = (64 queries) x head x batch, 4 waves; wave w owns queries 16w..16w+15.
// K staged once per block in XOR-swizzled LDS; S^T = K·Q^T; softmax in-register
// (band-masked, shfl_xor 16/32); P via LDS (wave-private rows, no barrier);
// O = P·V from swizzled Vt. OOB keys staged as zeros -> score 0 kept in softmax.
__device__ __forceinline__ int swz(int row, int colh) {
  int key = ((row & 7) ^ ((row >> 3) & 7)) << 4;
  return row * 128 + (((colh * 2) ^ key) >> 1);
}

__global__ __launch_bounds__(256) void attn_mfma(const _Float16* __restrict__ qkv,
                                                 _Float16* __restrict__ attn_out) {
  __shared__ _Float16 Vt[64 * 128];   // V^T: [dim][key], swizzled
  __shared__ _Float16 Pl[64 * 128];   // P:   [query][key], swizzled
  __shared__ _Float16 Ks[128 * 64];   // K:   [key][dim], slot = dimg ^ (key&7)

  const int b = blockIdx.z, h = blockIdx.y, q0 = blockIdx.x * 64;
  const int kv0 = q0 - 32;
  const int tid = threadIdx.x;
  const int lane = tid & 63, w = tid >> 6;
  const int fr = lane & 15, g = lane >> 4;

  // ---- stage V^T (transposed via registers) and K (row-major, swizzled slots)
  {
    const int jg = tid >> 3, dg = tid & 7;
    half8 vv[4];
#pragma unroll
    for (int i = 0; i < 4; i++) {
      int s = kv0 + jg * 4 + i;
      half8 z = {};
      if (s >= 0 && s < S_SZ)
        z = *(const half8*)(qkv + (size_t)(b * S_SZ + s) * NQKV + 2 * DIMM + h * HDIM + dg * 8);
      vv[i] = z;
    }
#pragma unroll
    for (int i2 = 0; i2 < 8; i2++) {
      half4 o;
      o[0] = vv[0][i2]; o[1] = vv[1][i2]; o[2] = vv[2][i2]; o[3] = vv[3][i2];
      *(half4*)(Vt + swz(dg * 8 + i2, jg * 4)) = o;
    }
    const int k0r = tid >> 3;            // 0..31
#pragma unroll
    for (int i = 0; i < 4; i++) {
      int key = k0r + i * 32;
      int s = kv0 + key;
      half8 z = {};
      if (s >= 0 && s < S_SZ)
        z = *(const half8*)(qkv + (size_t)(b * S_SZ + s) * NQKV + DIMM + h * HDIM + dg * 8);
      int slot = dg ^ (key & 7);
      *(half8*)(Ks + key * 64 + slot * 8) = z;
    }
  }

  // ---- Q fragments (per-wave, direct from global; small)
  const _Float16* qbase = qkv + (size_t)(b * S_SZ + q0 + 16 * w + fr) * NQKV + h * HDIM;
  half8 bq0 = *(const half8*)(qbase + 8 * g);        // dims  8g..+7
  half8 bq1 = *(const half8*)(qbase + 32 + 8 * g);   // dims 32+8g..+7

  __syncthreads();   // Ks + Vt staged

  // ---- S^T = K·Q^T from LDS
  f32x4 st[8];
#pragma unroll
  for (int kt = 0; kt < 8; kt++) st[kt] = (f32x4){0.f, 0.f, 0.f, 0.f};
#pragma unroll
  for (int kt = 0; kt < 8; kt++) {
    const int key = 16 * kt + fr;
    const int s0 = g ^ (key & 7), s1 = (g + 4) ^ (key & 7);
    half8 a0 = *(const half8*)(Ks + key * 64 + s0 * 8);
    half8 a1 = *(const half8*)(Ks + key * 64 + s1 * 8);
    st[kt] = __builtin_amdgcn_mfma_f32_16x16x32_f16(a0, bq0, st[kt], 0, 0, 0);
    st[kt] = __builtin_amdgcn_mfma_f32_16x16x32_f16(a1, bq1, st[kt], 0, 0, 0);
  }

  // ---- softmax over band [qi, qi+63]; lane's keys: 16kt+4g+j, query col = qi
  const int qi = 16 * w + fr;
  float m = -1e30f;
#pragma unroll
  for (int kt = 0; kt < 8; kt++)
#pragma unroll
    for (int j = 0; j < 4; j++) {
      int krel = 16 * kt + 4 * g + j;
      float scv = st[kt][j] * 0.125f;   // 1/sqrt(64)
      st[kt][j] = scv;
      if (krel >= qi && krel < qi + 64) m = fmaxf(m, scv);
    }
  m = fmaxf(m, __shfl_xor(m, 16));
  m = fmaxf(m, __shfl_xor(m, 32));
  float sum = 0.f;
#pragma unroll
  for (int kt = 0; kt < 8; kt++)
#pragma unroll
    for (int j = 0; j < 4; j++) {
      int krel = 16 * kt + 4 * g + j;
      float p = (krel >= qi && krel < qi + 64) ? __expf(st[kt][j] - m) : 0.f;
      st[kt][j] = p;
      sum += p;
    }
  sum += __shfl_xor(sum, 16);
  sum += __shfl_xor(sum, 32);
  const float inv = 1.f / sum;
#pragma unroll
  for (int kt = 0; kt < 8; kt++) {
    half4 o;
#pragma unroll
    for (int j = 0; j < 4; j++) o[j] = (_Float16)(st[kt][j] * inv);
    *(half4*)(Pl + swz(qi, 16 * kt + 4 * g)) = o;
  }
  // no barrier: Pl rows are wave-private (wave w writes/reads rows 16w..16w+15)

  // ---- O = P·V
  f32x4 acc[4];
#pragma unroll
  for (int dt = 0; dt < 4; dt++) acc[dt] = (f32x4){0.f, 0.f, 0.f, 0.f};
  half8 ap[4];
#pragma unroll
  for (int ks = 0; ks < 4; ks++)
    ap[ks] = *(const half8*)(Pl + swz(16 * w + fr, 32 * ks + 8 * g));
#pragma unroll
  for (int dt = 0; dt < 4; dt++)
#pragma unroll
    for (int ks = 0; ks < 4; ks++) {
      half8 bv = *(const half8*)(Vt + swz(16 * dt + fr, 32 * ks + 8 * g));
      acc[dt] = __builtin_amdgcn_mfma_f32_16x16x32_f16(ap[ks], bv, acc[dt], 0, 0, 0);
    }

#pragma unroll
  for (int dt = 0; dt < 4; dt++)
#pragma unroll
    for (int j = 0; j < 4; j++) {
      int q = q0 + 16 * w + 4 * g + j;
      attn_out[(size_t)(b * S_SZ + q) * DIMM + h * HDIM + 16 * dt + fr] = (_Float16)acc[dt][j];
    }
}

// ---------- launch ----------
extern "C" void kernel_launch(void* const* d_in, const int* in_sizes, int n_in,
                              void* d_out, int out_size, void* d_ws, size_t ws_size,
                              hipStream_t stream) {
  const float* x    = (const float*)d_in[0];
  const float* Wqkv = (const float*)d_in[1];
  const float* Wout = (const float*)d_in[2];

  char* ws = (char*)d_ws;
  _Float16* xb    = (_Float16*)(ws);                 // 4096*512  f16 =  4 MB
  _Float16* WqkvT = (_Float16*)(ws + 4194304);       // 1536*512  f16 = 1.5 MB
  _Float16* WoutT = (_Float16*)(ws + 5767168);       //  512*512  f16 = 0.5 MB
  _Float16* qkv   = (_Float16*)(ws + 6291456);       // 4096*1536 f16 = 12 MB
  _Float16* attn  = (_Float16*)(ws + 18874368);      // 4096*512  f16 =  4 MB

  prep_fused<<<3072, 256, 0, stream>>>(x, Wqkv, Wout, xb, WqkvT, WoutT);
  gemm_f16<128, true><<<dim3(12, 32), 256, 0, stream>>>(xb, WqkvT, (void*)qkv, MROWS, NQKV, DIMM);
  attn_mfma<<<dim3(32, NH, 2), 256, 0, stream>>>(qkv, attn);
  gemm_f16<64, false><<<dim3(4, 64), 256, 0, stream>>>(attn, WoutT, d_out, MROWS, DIMM, DIMM);
}